// Round 4
// baseline (998.560 us; speedup 1.0000x reference)
//
#include <hip/hip_runtime.h>

#define N0v 614400
#define N1v 40960
#define BATCHv 4096

typedef __attribute__((ext_vector_type(8))) short short8;
typedef __attribute__((ext_vector_type(4))) float floatx4;

static __device__ __forceinline__ float flog1p(float v) { return __logf(v + 1.0f); }
static __device__ __forceinline__ float sigf(float v) { return 1.0f / (1.0f + __expf(-v)); }
static __device__ __forceinline__ float tanhfast(float v) {
    return 1.0f - 2.0f / (__expf(2.0f * v) + 1.0f);
}
static __device__ __forceinline__ unsigned short f2bf(float f) {
    union { float f; unsigned u; } v; v.f = f;
    unsigned r = v.u + 0x7FFFu + ((v.u >> 16) & 1u);   // RNE
    return (unsigned short)(r >> 16);
}
static __device__ __forceinline__ float bf2f(unsigned short u) {
    return __uint_as_float(((unsigned)u) << 16);
}

// ---------------------------------------------------------------------------
// Weight pre-convert: fp32 -> bf16 copies in ws, plus bsum = b_ih + b_hh.
// ---------------------------------------------------------------------------
__global__ __launch_bounds__(256) void cvt_weights_kernel(
    const float* __restrict__ Wp, const float* __restrict__ Ws0,
    const float* __restrict__ Wn0, const float* __restrict__ Wih,
    const float* __restrict__ Whh, const float* __restrict__ bih,
    const float* __restrict__ bhh,
    unsigned short* __restrict__ Wpb, unsigned short* __restrict__ Ws0b,
    unsigned short* __restrict__ Wn0b, unsigned short* __restrict__ Wihb,
    unsigned short* __restrict__ Whhb, float* __restrict__ bsum)
{
    const int g = blockIdx.x * 256 + threadIdx.x;
    if (g < 16384)            Wpb[g] = f2bf(Wp[g]);
    else if (g < 49152)       Ws0b[g - 16384] = f2bf(Ws0[g - 16384]);
    else if (g < 81920)       Wn0b[g - 49152] = f2bf(Wn0[g - 49152]);
    else if (g < 344064)      Wihb[g - 81920] = f2bf(Wih[g - 81920]);
    else if (g < 606208)      Whhb[g - 344064] = f2bf(Whh[g - 344064]);
    else if (g < 607232) { const int i = g - 606208; bsum[i] = bih[i] + bhh[i]; }
}

// ---------------------------------------------------------------------------
// Stage A: pool-SAGE, STAGING-FREE. Per block: 4 nodes (60 gathered rows + 4
// pad) x 128 cols, K=128. MFMA fragments loaded directly from global:
// A: per-lane gather of x rows (fp32->log1p->bf16 in regs); B: Wpb rows from
// L1/L2 (32 KB, chip-hot). No LDS tile, no main-loop barriers -> compiler
// pipelines loads across all 4 K-steps. relu+max epilogue via LDS atomicMax.
// ---------------------------------------------------------------------------
__global__ __launch_bounds__(256) void pool_max_kernel(
    const float* __restrict__ x, const int* __restrict__ nbr0,
    const unsigned short* __restrict__ Wpb, const float* __restrict__ bp,
    unsigned short* __restrict__ hnb)
{
    __shared__ unsigned red[512];

    const int tid = threadIdx.x;
    const size_t base = (size_t)blockIdx.x * 60;
    const int lane = tid & 63, wv = tid >> 6;          // wv 0..3
    const int ml = lane & 15, q = lane >> 4, qk = q * 8;

    for (int i = tid; i < 512; i += 256) red[i] = 0u;

    const int row16 = wv * 16 + ml;                    // A row this lane feeds
    const int arow = (row16 < 60) ? row16 : 0;         // pad-safe
    const int node = nbr0[base + arow];
    const float* xr = x + (size_t)node * 128;

    floatx4 acc[8];
#pragma unroll
    for (int ct = 0; ct < 8; ++ct) acc[ct] = (floatx4){0.f, 0.f, 0.f, 0.f};

#pragma unroll
    for (int ks = 0; ks < 4; ++ks) {                   // K = 4 x 32
        const float4 f0 = *(const float4*)&xr[ks * 32 + qk];
        const float4 f1 = *(const float4*)&xr[ks * 32 + qk + 4];
        short8 a;
        a[0] = (short)f2bf(flog1p(f0.x)); a[1] = (short)f2bf(flog1p(f0.y));
        a[2] = (short)f2bf(flog1p(f0.z)); a[3] = (short)f2bf(flog1p(f0.w));
        a[4] = (short)f2bf(flog1p(f1.x)); a[5] = (short)f2bf(flog1p(f1.y));
        a[6] = (short)f2bf(flog1p(f1.z)); a[7] = (short)f2bf(flog1p(f1.w));
#pragma unroll
        for (int ct = 0; ct < 8; ++ct) {
            const short8 b = *(const short8*)&Wpb[(size_t)(ct * 16 + ml) * 128 + ks * 32 + qk];
            acc[ct] = __builtin_amdgcn_mfma_f32_16x16x32_bf16(a, b, acc[ct], 0, 0, 0);
        }
    }
    __syncthreads();                                   // red[] init visible
#pragma unroll
    for (int ct = 0; ct < 8; ++ct) {
        const int col = ct * 16 + ml;
        const float bb = bp[col];
#pragma unroll
        for (int r = 0; r < 4; ++r) {
            const int row = wv * 16 + q * 4 + r;
            if (row < 60) {
                const float v = fmaxf(acc[ct][r] + bb, 0.0f);
                atomicMax(&red[(row / 15) * 128 + col], __float_as_uint(v));
            }
        }
    }
    __syncthreads();
    for (int i = tid; i < 512; i += 256)
        hnb[(size_t)blockIdx.x * 512 + i] = f2bf(__uint_as_float(red[i]));
}

// ---------------------------------------------------------------------------
// Stage B: h0 = [log1p(x[:N1]) | h_neigh] @ [Ws0|Wn0]^T + b0, STAGING-FREE.
// A rows are contiguous (m0+16 per wave); B rows from L2 (256 KB, hot).
// Stores pre-BN bf16 + fused per-column sum/sumsq partials.
// ---------------------------------------------------------------------------
__global__ __launch_bounds__(256) void h0_kernel(
    const float* __restrict__ x, const unsigned short* __restrict__ hnb,
    const unsigned short* __restrict__ Ws0b, const unsigned short* __restrict__ Wn0b,
    const float* __restrict__ b0, unsigned short* __restrict__ h0bf,
    float* __restrict__ bn_sum, float* __restrict__ bn_sq)
{
    __shared__ float scr[4096];   // 16 KB epilogue scratch

    const int tid = threadIdx.x;
    const int m0 = blockIdx.x * 64, c0 = blockIdx.y * 128;
    const int lane = tid & 63, wv = tid >> 6;
    const int ml = lane & 15, q = lane >> 4, qk = q * 8;

    const int arow = m0 + wv * 16 + ml;
    const float* xr = x + (size_t)arow * 128;
    const unsigned short* hr = hnb + (size_t)arow * 128;

    floatx4 acc[8];
#pragma unroll
    for (int ct = 0; ct < 8; ++ct) acc[ct] = (floatx4){0.f, 0.f, 0.f, 0.f};

#pragma unroll
    for (int ks = 0; ks < 4; ++ks) {                   // K 0..127: log1p(x)
        const float4 f0 = *(const float4*)&xr[ks * 32 + qk];
        const float4 f1 = *(const float4*)&xr[ks * 32 + qk + 4];
        short8 a;
        a[0] = (short)f2bf(flog1p(f0.x)); a[1] = (short)f2bf(flog1p(f0.y));
        a[2] = (short)f2bf(flog1p(f0.z)); a[3] = (short)f2bf(flog1p(f0.w));
        a[4] = (short)f2bf(flog1p(f1.x)); a[5] = (short)f2bf(flog1p(f1.y));
        a[6] = (short)f2bf(flog1p(f1.z)); a[7] = (short)f2bf(flog1p(f1.w));
#pragma unroll
        for (int ct = 0; ct < 8; ++ct) {
            const short8 b = *(const short8*)&Ws0b[(size_t)(c0 + ct * 16 + ml) * 128 + ks * 32 + qk];
            acc[ct] = __builtin_amdgcn_mfma_f32_16x16x32_bf16(a, b, acc[ct], 0, 0, 0);
        }
    }
#pragma unroll
    for (int ks = 0; ks < 4; ++ks) {                   // K 128..255: h_neigh
        const short8 a = *(const short8*)&hr[ks * 32 + qk];
#pragma unroll
        for (int ct = 0; ct < 8; ++ct) {
            const short8 b = *(const short8*)&Wn0b[(size_t)(c0 + ct * 16 + ml) * 128 + ks * 32 + qk];
            acc[ct] = __builtin_amdgcn_mfma_f32_16x16x32_bf16(a, b, acc[ct], 0, 0, 0);
        }
    }

#pragma unroll
    for (int ct = 0; ct < 8; ++ct) {
        const int col = ct * 16 + ml, cg = c0 + col;
        const float bb = b0[cg];
        float s = 0.f, sq = 0.f;
#pragma unroll
        for (int r = 0; r < 4; ++r) {
            const int row = wv * 16 + q * 4 + r;
            const float v = acc[ct][r] + bb;
            h0bf[(size_t)(m0 + row) * 256 + cg] = f2bf(v);
            s += v; sq += v * v;
        }
        scr[(wv * 4 + q) * 128 + col] = s;
        scr[2048 + (wv * 4 + q) * 128 + col] = sq;
    }
    __syncthreads();
    if (tid < 128) {
        float s = 0.f, sq = 0.f;
#pragma unroll
        for (int j = 0; j < 16; ++j) {
            s += scr[j * 128 + tid];
            sq += scr[2048 + j * 128 + tid];
        }
        atomicAdd(&bn_sum[c0 + tid], s);
        atomicAdd(&bn_sq[c0 + tid], sq);
    }
}

__global__ void bn_stats_kernel(const float* __restrict__ bn_sum, const float* __restrict__ bn_sq,
                                const float* __restrict__ gamma, const float* __restrict__ beta,
                                float* __restrict__ scale, float* __restrict__ shift)
{
    const int c = threadIdx.x;   // 256
    const float inv_n = 1.0f / (float)N1v;
    const float mu = bn_sum[c] * inv_n;
    const float var = bn_sq[c] * inv_n - mu * mu;
    const float rs = rsqrtf(var + 1e-5f);
    const float sc = rs * gamma[c];
    scale[c] = sc;
    shift[c] = beta[c] - mu * sc;
}

__global__ __launch_bounds__(256) void bn_apply_kernel(
    const unsigned short* __restrict__ h0bf, const float* __restrict__ scale,
    const float* __restrict__ shift, unsigned short* __restrict__ h0nbf)
{
    const int gid = blockIdx.x * 256 + threadIdx.x;   // over N1*256/8
    const int c0 = (gid * 8) & 255;
    const short8 v = *(const short8*)&h0bf[(size_t)gid * 8];
    short8 o;
#pragma unroll
    for (int j = 0; j < 8; ++j) {
        const float f = bf2f((unsigned short)v[j]);
        o[j] = (short)f2bf(fmaxf(fmaf(f, scale[c0 + j], shift[c0 + j]), 0.0f));
    }
    *(short8*)&h0nbf[(size_t)gid * 8] = o;
}

// ---------------------------------------------------------------------------
// Fused LSTM step, STAGING-FREE: gates GEMM + pointwise, zero LDS, zero
// barriers. Gate-interleaved columns (block = all 4 gates x 32 h-cols ->
// pointwise in registers). A: per-lane gather from h0nbf (L3-hot, 21 MB) and
// h_prev (coalesced); B: Wihb/Whhb rows from L2 (1 MB, hot). t=0 skips the
// h_prev K-half. M=4096 (64/blk), h-cols 256 (32/blk via gridDim.y=8).
// ---------------------------------------------------------------------------
__global__ __launch_bounds__(256) void lstm_step_kernel(
    const unsigned short* __restrict__ h0nbf, const int* __restrict__ nbr1,
    const unsigned short* __restrict__ hbprev, const unsigned short* __restrict__ Wihb,
    const unsigned short* __restrict__ Whhb, const float* __restrict__ bsum,
    float* __restrict__ cst, unsigned short* __restrict__ hb, int t)
{
    const int tid = threadIdx.x;
    const int m0 = blockIdx.x * 64, c0h = blockIdx.y * 32;
    const int lane = tid & 63, wv = tid >> 6;
    const int ml = lane & 15, q = lane >> 4, qk = q * 8;

    const int arow = m0 + wv * 16 + ml;
    const int node = nbr1[(size_t)arow * 10 + t];
    const unsigned short* ag = h0nbf + (size_t)node * 256;
    const unsigned short* ah = hbprev + (size_t)arow * 256;

    // W element offsets: ct -> gate g=ct>>1, h-half hg=ct&1
    size_t wroff[8];
#pragma unroll
    for (int ct = 0; ct < 8; ++ct)
        wroff[ct] = (size_t)((ct >> 1) * 256 + c0h + (ct & 1) * 16 + ml) * 256;

    floatx4 acc[8];
#pragma unroll
    for (int ct = 0; ct < 8; ++ct) acc[ct] = (floatx4){0.f, 0.f, 0.f, 0.f};

#pragma unroll
    for (int ks = 0; ks < 8; ++ks) {                   // K 0..255: gathered h0n
        const short8 a = *(const short8*)&ag[ks * 32 + qk];
#pragma unroll
        for (int ct = 0; ct < 8; ++ct) {
            const short8 b = *(const short8*)&Wihb[wroff[ct] + ks * 32 + qk];
            acc[ct] = __builtin_amdgcn_mfma_f32_16x16x32_bf16(a, b, acc[ct], 0, 0, 0);
        }
    }
    if (t > 0) {                                       // K 256..511: h_prev
#pragma unroll
        for (int ks = 0; ks < 8; ++ks) {
            const short8 a = *(const short8*)&ah[ks * 32 + qk];
#pragma unroll
            for (int ct = 0; ct < 8; ++ct) {
                const short8 b = *(const short8*)&Whhb[wroff[ct] + ks * 32 + qk];
                acc[ct] = __builtin_amdgcn_mfma_f32_16x16x32_bf16(a, b, acc[ct], 0, 0, 0);
            }
        }
    }

    // pointwise LSTM epilogue, fully in registers
#pragma unroll
    for (int hg = 0; hg < 2; ++hg) {
        const int hcol = hg * 16 + ml;
        const float bi = bsum[c0h + hcol];
        const float bf_ = bsum[256 + c0h + hcol];
        const float bg = bsum[512 + c0h + hcol];
        const float bo = bsum[768 + c0h + hcol];
#pragma unroll
        for (int r = 0; r < 4; ++r) {
            const int row = wv * 16 + q * 4 + r;
            const size_t idx = (size_t)(m0 + row) * 256 + c0h + hcol;
            const float gi = acc[0 + hg][r] + bi;
            const float gf = acc[2 + hg][r] + bf_;
            const float gg = acc[4 + hg][r] + bg;
            const float go = acc[6 + hg][r] + bo;
            float c = sigf(gi) * tanhfast(gg);
            if (t > 0) c += sigf(gf) * cst[idx];
            cst[idx] = c;
            hb[idx] = f2bf(sigf(go) * tanhfast(c));
        }
    }
}

// ---------------------------------------------------------------------------
// Stage E: out = h0n[:B] @ W_self1^T + hT @ W_neigh1^T + b1   [4096 x 32]
// 8 rows/block staged once in LDS, then 256 dot products.
// ---------------------------------------------------------------------------
__global__ __launch_bounds__(256) void out_kernel(
    const unsigned short* __restrict__ h0nbf, const unsigned short* __restrict__ hTb,
    const float* __restrict__ Ws1, const float* __restrict__ Wn1,
    const float* __restrict__ b1, float* __restrict__ out)
{
    __shared__ unsigned short aS[8 * 256];
    __shared__ unsigned short hS[8 * 256];

    const int tid = threadIdx.x;
    const int m0 = blockIdx.x * 8;

    for (int i = tid; i < 512; i += 256) {     // 2 x (8 rows x 32 segs)
        const int sel = i >> 8, idx = i & 255;
        const int row = idx >> 5, seg = idx & 31;
        if (sel == 0)
            *(short8*)&aS[row * 256 + seg * 8] =
                *(const short8*)&h0nbf[(size_t)(m0 + row) * 256 + seg * 8];
        else
            *(short8*)&hS[row * 256 + seg * 8] =
                *(const short8*)&hTb[(size_t)(m0 + row) * 256 + seg * 8];
    }
    __syncthreads();

    const int row = tid >> 5, cls = tid & 31;
    const float* w0 = Ws1 + (size_t)cls * 256;
    const float* w1 = Wn1 + (size_t)cls * 256;
    const unsigned short* a0 = &aS[row * 256];
    const unsigned short* a1 = &hS[row * 256];
    float s = b1[cls];
#pragma unroll 4
    for (int k8 = 0; k8 < 32; ++k8) {
        const short8 av = *(const short8*)&a0[k8 * 8];
        const short8 bv = *(const short8*)&a1[k8 * 8];
        const float4 wa0 = *(const float4*)&w0[k8 * 8];
        const float4 wa1 = *(const float4*)&w0[k8 * 8 + 4];
        const float4 wb0 = *(const float4*)&w1[k8 * 8];
        const float4 wb1 = *(const float4*)&w1[k8 * 8 + 4];
        s += bf2f((unsigned short)av[0]) * wa0.x + bf2f((unsigned short)av[1]) * wa0.y;
        s += bf2f((unsigned short)av[2]) * wa0.z + bf2f((unsigned short)av[3]) * wa0.w;
        s += bf2f((unsigned short)av[4]) * wa1.x + bf2f((unsigned short)av[5]) * wa1.y;
        s += bf2f((unsigned short)av[6]) * wa1.z + bf2f((unsigned short)av[7]) * wa1.w;
        s += bf2f((unsigned short)bv[0]) * wb0.x + bf2f((unsigned short)bv[1]) * wb0.y;
        s += bf2f((unsigned short)bv[2]) * wb0.z + bf2f((unsigned short)bv[3]) * wb0.w;
        s += bf2f((unsigned short)bv[4]) * wb1.x + bf2f((unsigned short)bv[5]) * wb1.y;
        s += bf2f((unsigned short)bv[6]) * wb1.z + bf2f((unsigned short)bv[7]) * wb1.w;
    }
    out[(size_t)(m0 + row) * 32 + cls] = s;
}

extern "C" void kernel_launch(void* const* d_in, const int* in_sizes, int n_in,
                              void* d_out, int out_size, void* d_ws, size_t ws_size,
                              hipStream_t stream)
{
    const float* x        = (const float*)d_in[0];
    const int*   nbr0     = (const int*)d_in[1];
    const int*   nbr1     = (const int*)d_in[2];
    const float* W_pool   = (const float*)d_in[3];
    const float* b_pool   = (const float*)d_in[4];
    const float* W_self0  = (const float*)d_in[5];
    const float* W_neigh0 = (const float*)d_in[6];
    const float* b0       = (const float*)d_in[7];
    const float* gamma0   = (const float*)d_in[8];
    const float* beta0    = (const float*)d_in[9];
    const float* W_ih     = (const float*)d_in[10];
    const float* W_hh     = (const float*)d_in[11];
    const float* b_ih     = (const float*)d_in[12];
    const float* b_hh     = (const float*)d_in[13];
    const float* W_self1  = (const float*)d_in[14];
    const float* W_neigh1 = (const float*)d_in[15];
    const float* b1       = (const float*)d_in[16];
    float* out = (float*)d_out;

    // ws layout (bytes) — R1 layout (h0nbf materialized again).
    char* ws = (char*)d_ws;
    unsigned short* h0bf  = (unsigned short*)(ws);               // 20,971,520 B
    unsigned short* hnb   = (unsigned short*)(ws + 20971520);    // 10,485,760 B
    unsigned short* h0nbf = (unsigned short*)(ws + 31457280);    // 20,971,520 B
    float*          cst   = (float*)(ws + 52428800);             //  4,194,304 B
    unsigned short* hb0   = (unsigned short*)(ws + 56623104);    //  2,097,152 B
    unsigned short* hb1   = (unsigned short*)(ws + 58720256);    //  2,097,152 B
    unsigned short* Wpb   = (unsigned short*)(ws + 60817408);    //     32,768 B
    unsigned short* Ws0b  = (unsigned short*)(ws + 60850176);    //     65,536 B
    unsigned short* Wn0b  = (unsigned short*)(ws + 60915712);    //     65,536 B
    unsigned short* Wihb  = (unsigned short*)(ws + 60981248);    //    524,288 B
    unsigned short* Whhb  = (unsigned short*)(ws + 61505536);    //    524,288 B
    float*          bsum  = (float*)(ws + 62029824);             //      4,096 B
    float*          bn_sum   = (float*)(ws + 62033920);
    float*          bn_sq    = (float*)(ws + 62034944);
    float*          bn_scale = (float*)(ws + 62035968);
    float*          bn_shift = (float*)(ws + 62036992);

    hipMemsetAsync(bn_sum, 0, 2048, stream);        // bn_sum + bn_sq

    cvt_weights_kernel<<<2372, 256, 0, stream>>>(W_pool, W_self0, W_neigh0, W_ih, W_hh,
                                                 b_ih, b_hh, Wpb, Ws0b, Wn0b, Wihb, Whhb, bsum);
    pool_max_kernel<<<N1v / 4, 256, 0, stream>>>(x, nbr0, Wpb, b_pool, hnb);
    h0_kernel<<<dim3(N1v / 64, 2), 256, 0, stream>>>(x, hnb, Ws0b, Wn0b, b0,
                                                     h0bf, bn_sum, bn_sq);
    bn_stats_kernel<<<1, 256, 0, stream>>>(bn_sum, bn_sq, gamma0, beta0, bn_scale, bn_shift);
    bn_apply_kernel<<<(N1v * 256 / 8) / 256, 256, 0, stream>>>(h0bf, bn_scale, bn_shift, h0nbf);

    for (int t = 0; t < 10; ++t) {
        const unsigned short* hp = (t & 1) ? hb1 : hb0;
        unsigned short*       hn = (t & 1) ? hb0 : hb1;
        lstm_step_kernel<<<dim3(BATCHv / 64, 8), 256, 0, stream>>>(
            h0nbf, nbr1, hp, Wihb, Whhb, bsum, cst, hn, t);
    }
    // t=9 wrote hb0 -> final hidden state
    out_kernel<<<BATCHv / 8, 256, 0, stream>>>(h0nbf, hb0, W_self1, W_neigh1, b1, out);
}